// Round 2
// baseline (78.974 us; speedup 1.0000x reference)
//
#include <hip/hip_runtime.h>
#include <hip/hip_bf16.h>

// ---- dtype switches (round-1 evidence: inputs fp32, output fp32) ----
#define IN_BF16 0
#define OUT_BF16 0

#if IN_BF16
typedef __hip_bfloat16 in_t;
__device__ __forceinline__ float ld(const in_t* p) { return __bfloat162float(*p); }
#else
typedef float in_t;
__device__ __forceinline__ float ld(const in_t* p) { return *p; }
#endif

#if OUT_BF16
typedef __hip_bfloat16 out_t;
__device__ __forceinline__ void st(out_t* p, float v) { *p = __float2bfloat16(v); }
#else
typedef float out_t;
__device__ __forceinline__ void st(out_t* p, float v) { *p = v; }
#endif

#define N_SP 16
#define D 32
#define TOPK 4
#define WPAD 36   // padded row stride (floats): bank = (36*row + k) % 32 varies per row

__global__ __launch_bounds__(256) void UltraSparseGNN_kernel(
    const in_t* __restrict__ x,
    const in_t* __restrict__ w_in,
    const in_t* __restrict__ emb,
    const in_t* __restrict__ w0,
    const in_t* __restrict__ a0,
    const in_t* __restrict__ w1,
    const in_t* __restrict__ a1,
    const in_t* __restrict__ w_out,
    const in_t* __restrict__ b_out,
    const in_t* __restrict__ r_int,
    out_t* __restrict__ out,
    int total)
{
    __shared__ float s_w0[D][WPAD];   // gat_w0, row-major [j][k]
    __shared__ float s_w1[D][WPAD];
    __shared__ float s_emb[N_SP][WPAD];
    __shared__ float s_c0[D], s_c1[D];        // c = w^T @ a[d:]
    __shared__ float s_win0[D], s_win1[D];    // w_in[:,0], w_in[:,1]
    __shared__ float s_wout[D];
    __shared__ float s_r[N_SP];
    __shared__ float s_b;

    const int tid = threadIdx.x;

    // ---- stage constants into LDS (once per block) ----
    for (int i = tid; i < D * D; i += 256) {
        int j = i >> 5, k = i & 31;
        s_w0[j][k] = ld(&w0[i]);
        s_w1[j][k] = ld(&w1[i]);
    }
    for (int i = tid; i < N_SP * D; i += 256) {
        int n = i >> 5, k = i & 31;
        s_emb[n][k] = ld(&emb[i]);
    }
    if (tid < D) {
        // c[k] = sum_j a2[j] * w[j][k]   (s_j = hw @ a2 = h @ c)
        float acc0 = 0.f, acc1 = 0.f;
        for (int j = 0; j < D; ++j) {
            acc0 += ld(&a0[D + j]) * ld(&w0[j * D + tid]);
            acc1 += ld(&a1[D + j]) * ld(&w1[j * D + tid]);
        }
        s_c0[tid] = acc0;
        s_c1[tid] = acc1;
        s_win0[tid] = ld(&w_in[tid * 2 + 0]);
        s_win1[tid] = ld(&w_in[tid * 2 + 1]);
        s_wout[tid] = ld(&w_out[tid]);
    }
    if (tid < N_SP) s_r[tid] = ld(&r_int[tid]);
    if (tid == 0)  s_b = ld(&b_out[0]);
    __syncthreads();

    const int gt = blockIdx.x * 256 + tid;   // == graph*16 + node (x is (B,T,N) flat)
    if (gt >= total) return;
    const int node = tid & 15;

    // ---- input projection: h = [x, log(clip(x))] @ w_in^T + emb[node] ----
    const float xv = ld(&x[gt]);
    const float lx = __logf(fmaxf(xv, 1e-6f));
    float h[D];
    #pragma unroll
    for (int k = 0; k < D; ++k)
        h[k] = fmaf(xv, s_win0[k], fmaf(lx, s_win1[k], s_emb[node][k]));

    // ---- two GAT layers; attn is identical for every row of a graph ----
    #pragma unroll
    for (int L = 0; L < 2; ++L) {
        const float* c = L ? s_c1 : s_c0;
        const float (*w)[WPAD] = L ? s_w1 : s_w0;

        // s_j for this node
        float s = 0.f;
        #pragma unroll
        for (int k = 0; k < D; ++k) s = fmaf(h[k], c[k], s);

        // rank of this node's score within the 16-node graph
        // (ties: lower index wins, matching jax.lax.top_k)
        int rank = 0;
        #pragma unroll
        for (int m = 0; m < N_SP; ++m) {
            float so = __shfl(s, m, N_SP);
            rank += (so > s) || (so == s && m < node);
        }
        const bool keep = rank < TOPK;

        // softmax over kept scores (group max == max of kept, since top-1 is kept)
        float mx = s;
        #pragma unroll
        for (int d = 8; d >= 1; d >>= 1) mx = fmaxf(mx, __shfl_xor(mx, d, N_SP));
        float e = keep ? __expf(s - mx) : 0.f;
        float den = e;
        #pragma unroll
        for (int d = 8; d >= 1; d >>= 1) den += __shfl_xor(den, d, N_SP);
        const float attn = e / den;

        // u = sum_m attn_m * h_m  (butterfly over the 16-lane group)
        float u[D];
        #pragma unroll
        for (int k = 0; k < D; ++k) u[k] = attn * h[k];
        #pragma unroll
        for (int d = 8; d >= 1; d >>= 1) {
            #pragma unroll
            for (int k = 0; k < D; ++k) u[k] += __shfl_xor(u[k], d, N_SP);
        }

        // v = u @ w^T ; this lane computes rows j=node and j=node+16
        float v0 = 0.f, v1 = 0.f;
        #pragma unroll
        for (int k = 0; k < D; ++k) {
            v0 = fmaf(u[k], w[node][k], v0);
            v1 = fmaf(u[k], w[node + 16][k], v1);
        }

        // residual add: h[n] += v (gather the full v across the group)
        #pragma unroll
        for (int m = 0; m < N_SP; ++m) {
            h[m]      += __shfl(v0, m, N_SP);
            h[m + 16] += __shfl(v1, m, N_SP);
        }
    }

    // ---- output head ----
    float o = s_b;
    #pragma unroll
    for (int k = 0; k < D; ++k) o = fmaf(h[k], s_wout[k], o);
    o += s_r[node];
    st(&out[gt], o);
}

extern "C" void kernel_launch(void* const* d_in, const int* in_sizes, int n_in,
                              void* d_out, int out_size, void* d_ws, size_t ws_size,
                              hipStream_t stream) {
    const in_t* x     = (const in_t*)d_in[0];
    const in_t* w_in  = (const in_t*)d_in[1];
    const in_t* emb   = (const in_t*)d_in[2];
    const in_t* w0    = (const in_t*)d_in[3];
    const in_t* a0    = (const in_t*)d_in[4];
    const in_t* w1    = (const in_t*)d_in[5];
    const in_t* a1    = (const in_t*)d_in[6];
    const in_t* w_out = (const in_t*)d_in[7];
    const in_t* b_out = (const in_t*)d_in[8];
    const in_t* r_int = (const in_t*)d_in[9];

    const int total = in_sizes[0];            // B*T*N = 1048576
    const int blocks = (total + 255) / 256;
    UltraSparseGNN_kernel<<<blocks, 256, 0, stream>>>(
        x, w_in, emb, w0, a0, w1, a1, w_out, b_out, r_int,
        (out_t*)d_out, total);
}

// Round 3
// 18.575 us; speedup vs baseline: 4.2516x; 4.2516x over previous
//
#include <hip/hip_runtime.h>

#define TOPK 4

// ---------------- DPP helpers (VALU-pipe cross-lane, 16-lane rows) ----------------
// ctrl: quad_perm xor1 = 0xB1 ([1,0,3,2]), xor2 = 0x4E ([2,3,0,1]),
//       row_half_mirror = 0x141 (lane^7), row_ror:8 = 0x128 (lane^8), row_ror:N = 0x120+N
template<int CTRL>
__device__ __forceinline__ float dppf(float v) {
    return __builtin_bit_cast(float,
        __builtin_amdgcn_update_dpp(0, __builtin_bit_cast(int, v), CTRL, 0xF, 0xF, true));
}

// butterfly reduce over each 16-lane group; result in all lanes
__device__ __forceinline__ float gsum16(float v) {
    v += dppf<0xB1>(v);   // xor1
    v += dppf<0x4E>(v);   // xor2
    v += dppf<0x141>(v);  // xor7 (crosses quads within 8)
    v += dppf<0x128>(v);  // xor8
    return v;
}
__device__ __forceinline__ float gmax16(float v) {
    v = fmaxf(v, dppf<0xB1>(v));
    v = fmaxf(v, dppf<0x4E>(v));
    v = fmaxf(v, dppf<0x141>(v));
    v = fmaxf(v, dppf<0x128>(v));
    return v;
}

// rank of this lane's s within its 16-lane group (ties: lower node index wins,
// matching jax.lax.top_k). row_ror:o assumed D[i]=S[(i-o)&15]; direction only
// affects exact-tie cases (measure-zero on this data).
__device__ __forceinline__ int rank16(float s, int lane) {
    int rank = 0;
#define RS(o) { float t = dppf<0x120 + (o)>(s); int m = (lane - (o)) & 15; \
                rank += ((t > s) || (t == s && m < lane)) ? 1 : 0; }
    RS(1) RS(2) RS(3) RS(4) RS(5) RS(6) RS(7) RS(8)
    RS(9) RS(10) RS(11) RS(12) RS(13) RS(14) RS(15)
#undef RS
    return rank;
}

// one collapsed GAT layer: from per-lane score s, produce the three
// attn-weighted group sums (X = sum attn*x, Lo = sum attn*lnx, A = sum attn*ce)
__device__ __forceinline__ void gat_layer(float s, int lane, float xv, float lx, float ce,
                                          float& X, float& Lo, float& A) {
    int r = rank16(s, lane);
    float mx = gmax16(s);                       // global max == max of kept (top-1 kept)
    float e = (r < TOPK) ? __expf(s - mx) : 0.f;
    float rden = __builtin_amdgcn_rcpf(gsum16(e));  // den in [1,4]
    float attn = e * rden;
    X  = gsum16(attn * xv);
    Lo = gsum16(attn * lx);
    A  = gsum16(attn * ce);
}

// ---------------- setup: contract all weights into 90 scalars ----------------
// cst layout: [0..9] scalars {a0,b0,a1,b1,kx,kl,C0X,C0L,C1X,C1L},
// [10..25] gamma0[n], [26..41] gamma1[n], [42..57] ce0[n], [58..73] ce1[n], [74..89] keR[n]
__global__ __launch_bounds__(128) void UltraSparseGNN_setup(
    const float* __restrict__ w_in, const float* __restrict__ emb,
    const float* __restrict__ w0,   const float* __restrict__ a0,
    const float* __restrict__ w1,   const float* __restrict__ a1,
    const float* __restrict__ w_out, const float* __restrict__ b_out,
    const float* __restrict__ r_int, float* __restrict__ cst)
{
    __shared__ float g0[32], g1[32], c0[32], c1[32], gs[32];
    const int tid = threadIdx.x;
    const int k = tid & 31, grp = tid >> 5;
    if (grp == 0) { float a = 0; for (int j = 0; j < 32; ++j) a = fmaf(w_out[j],  w0[j*32+k], a); g0[k] = a; }
    if (grp == 1) { float a = 0; for (int j = 0; j < 32; ++j) a = fmaf(w_out[j],  w1[j*32+k], a); g1[k] = a; }
    if (grp == 2) { float a = 0; for (int j = 0; j < 32; ++j) a = fmaf(a0[32+j],  w0[j*32+k], a); c0[k] = a; }
    if (grp == 3) { float a = 0; for (int j = 0; j < 32; ++j) a = fmaf(a1[32+j],  w1[j*32+k], a); c1[k] = a; }
    __syncthreads();
    if (grp == 0) { float a = 0; for (int j = 0; j < 32; ++j) a = fmaf(g1[j], w0[j*32+k], a); gs[k] = g0[k] + a; } // gs = g0 + W0^T g1
    __syncthreads();

    if (tid < 10) {  // scalar dots; win0[j]=w_in[2j], win1[j]=w_in[2j+1]
        float acc = 0;
        switch (tid) {
            case 0: for (int j = 0; j < 32; ++j) acc = fmaf(w_in[2*j],   c0[j],   acc); break; // alpha0
            case 1: for (int j = 0; j < 32; ++j) acc = fmaf(w_in[2*j+1], c0[j],   acc); break; // beta0
            case 2: for (int j = 0; j < 32; ++j) acc = fmaf(w_in[2*j],   c1[j],   acc); break; // alpha1
            case 3: for (int j = 0; j < 32; ++j) acc = fmaf(w_in[2*j+1], c1[j],   acc); break; // beta1
            case 4: for (int j = 0; j < 32; ++j) acc = fmaf(w_in[2*j],   w_out[j], acc); break; // kx
            case 5: for (int j = 0; j < 32; ++j) acc = fmaf(w_in[2*j+1], w_out[j], acc); break; // kl
            case 6: for (int j = 0; j < 32; ++j) acc = fmaf(w_in[2*j],   gs[j],   acc); break; // C0X
            case 7: for (int j = 0; j < 32; ++j) acc = fmaf(w_in[2*j+1], gs[j],   acc); break; // C0L
            case 8: for (int j = 0; j < 32; ++j) acc = fmaf(w_in[2*j],   g1[j],   acc); break; // C1X
            case 9: for (int j = 0; j < 32; ++j) acc = fmaf(w_in[2*j+1], g1[j],   acc); break; // C1L
        }
        cst[tid] = acc;
    }
    if (tid >= 16 && tid < 32) { int n = tid-16; float a = 0; for (int j = 0; j < 32; ++j) a = fmaf(emb[n*32+j], c0[j], a); cst[10+n] = a; }
    if (tid >= 32 && tid < 48) { int n = tid-32; float a = 0; for (int j = 0; j < 32; ++j) a = fmaf(emb[n*32+j], c1[j], a); cst[26+n] = a; }
    if (tid >= 48 && tid < 64) { int n = tid-48; float a = 0; for (int j = 0; j < 32; ++j) a = fmaf(emb[n*32+j], gs[j], a); cst[42+n] = a; }
    if (tid >= 64 && tid < 80) { int n = tid-64; float a = 0; for (int j = 0; j < 32; ++j) a = fmaf(emb[n*32+j], g1[j], a); cst[58+n] = a; }
    if (tid >= 80 && tid < 96) { int n = tid-80; float a = 0; for (int j = 0; j < 32; ++j) a = fmaf(emb[n*32+j], w_out[j], a); cst[74+n] = a + b_out[0] + r_int[n]; }
}

// ---------------- main: 1 thread per (graph, node); all cross-lane via DPP ----------------
__global__ __launch_bounds__(256) void UltraSparseGNN_main(
    const float* __restrict__ x, const float* __restrict__ cst,
    float* __restrict__ out, int total)
{
    __shared__ float L[90];
    const int tid = threadIdx.x;
    if (tid < 90) L[tid] = cst[tid];
    __syncthreads();

    const int gt = blockIdx.x * 256 + tid;
    if (gt >= total) return;
    const int lane = tid & 15;

    const float xv = x[gt];
    const float lx = __logf(fmaxf(xv, 1e-6f));

    const float s0 = fmaf(L[0], xv, fmaf(L[1], lx, L[10 + lane]));
    const float s1 = fmaf(L[2], xv, fmaf(L[3], lx, L[26 + lane]));

    float X0, Lb0, A0, X1, Lb1, A1;
    gat_layer(s0, lane, xv, lx, L[42 + lane], X0, Lb0, A0);
    gat_layer(s1, lane, xv, lx, L[58 + lane], X1, Lb1, A1);

    float o = fmaf(L[4], xv, fmaf(L[5], lx, L[74 + lane]));
    o = fmaf(X0, L[6], o);
    o = fmaf(Lb0, L[7], o);
    o += A0;
    o = fmaf(X1, L[8], o);
    o = fmaf(Lb1, L[9], o);
    o += A1;
    out[gt] = o;
}

extern "C" void kernel_launch(void* const* d_in, const int* in_sizes, int n_in,
                              void* d_out, int out_size, void* d_ws, size_t ws_size,
                              hipStream_t stream) {
    const float* x     = (const float*)d_in[0];
    const float* w_in  = (const float*)d_in[1];
    const float* emb   = (const float*)d_in[2];
    const float* w0    = (const float*)d_in[3];
    const float* a0    = (const float*)d_in[4];
    const float* w1    = (const float*)d_in[5];
    const float* a1    = (const float*)d_in[6];
    const float* w_out = (const float*)d_in[7];
    const float* b_out = (const float*)d_in[8];
    const float* r_int = (const float*)d_in[9];

    float* cst = (float*)d_ws;   // 90 floats of precomputed constants

    UltraSparseGNN_setup<<<1, 128, 0, stream>>>(
        w_in, emb, w0, a0, w1, a1, w_out, b_out, r_int, cst);

    const int total = in_sizes[0];              // B*T*N = 1048576
    const int blocks = (total + 255) / 256;
    UltraSparseGNN_main<<<blocks, 256, 0, stream>>>(x, cst, (float*)d_out, total);
}

// Round 4
// 16.183 us; speedup vs baseline: 4.8801x; 1.1478x over previous
//
#include <hip/hip_runtime.h>

#define TOPK 4

// ---------------- quad-level DPP helpers (VALU pipe, 4-lane groups) ----------------
// quad_perm encodings: D[i] = S[sel_i], ctrl = sel0|sel1<<2|sel2<<4|sel3<<6
#define QP_XOR1 0xB1   // [1,0,3,2]
#define QP_XOR2 0x4E   // [2,3,0,1]
#define QP_ROT1 0x93   // [3,0,1,2]: lane q reads lane (q-1)&3
#define QP_ROT3 0x39   // [1,2,3,0]: lane q reads lane (q-3)&3

template<int CTRL>
__device__ __forceinline__ int dpp_i(int v) {
    return __builtin_amdgcn_update_dpp(0, v, CTRL, 0xF, 0xF, true);
}
template<int CTRL>
__device__ __forceinline__ float dpp_f(float v) {
    return __builtin_bit_cast(float, dpp_i<CTRL>(__builtin_bit_cast(int, v)));
}
__device__ __forceinline__ float qsum(float v) {   // sum over 4-lane quad, all lanes get it
    v += dpp_f<QP_XOR1>(v);
    v += dpp_f<QP_XOR2>(v);
    return v;
}

// ---- one collapsed GAT layer on a 4-lane x 4-value graph ----
// s[4]: this lane's 4 node scores; outputs X=Σattn·x, Lo=Σattn·lx, A=Σattn·ce (quad-uniform).
// Rank uses monotone-u32 keys: key order == (score, -node) lexicographic tie rule of jax.lax.top_k.
__device__ __forceinline__ void gat4(const float s[4], const float xv[4], const float lx[4],
                                     const float ce[4], int q,
                                     float& X, float& Lo, float& A)
{
    uint32_t k[4];
    #pragma unroll
    for (int i = 0; i < 4; ++i) {
        int b = __float_as_int(s[i]);
        k[i] = (uint32_t)(b ^ ((b >> 31) | 0x80000000));  // order-preserving map (finite floats)
    }
    // self-quad pairs: j<i -> tie goes to j (lower node) -> use >=  (k_j > k_i - 1)
    int r[4];
    r[0] = (k[1] > k[0]) + (k[2] > k[0]) + (k[3] > k[0]);
    r[1] = (k[0] > k[1] - 1u) + (k[2] > k[1]) + (k[3] > k[1]);
    r[2] = (k[0] > k[2] - 1u) + (k[1] > k[2] - 1u) + (k[3] > k[2]);
    r[3] = (k[0] > k[3] - 1u) + (k[1] > k[3] - 1u) + (k[2] > k[3] - 1u);

    // cross-quad: foreign node m = qq*4+j, mine n = q*4+i; m<n <=> qq<q (uniform per rot).
    // cond = (t>k) || (t==k && qlt)  ==  t > (k - qlt)   [k==0 only for -NaN, impossible]
#define ROT_ACC(CTRL, ROT) { \
    const uint32_t qlt = (((q - (ROT)) & 3) < q) ? 1u : 0u; \
    const uint32_t t0 = (uint32_t)dpp_i<CTRL>((int)k[0]); \
    const uint32_t t1 = (uint32_t)dpp_i<CTRL>((int)k[1]); \
    const uint32_t t2 = (uint32_t)dpp_i<CTRL>((int)k[2]); \
    const uint32_t t3 = (uint32_t)dpp_i<CTRL>((int)k[3]); \
    const uint32_t h0 = k[0] - qlt, h1 = k[1] - qlt, h2 = k[2] - qlt, h3 = k[3] - qlt; \
    r[0] += (t0 > h0) + (t1 > h0) + (t2 > h0) + (t3 > h0); \
    r[1] += (t0 > h1) + (t1 > h1) + (t2 > h1) + (t3 > h1); \
    r[2] += (t0 > h2) + (t1 > h2) + (t2 > h2) + (t3 > h2); \
    r[3] += (t0 > h3) + (t1 > h3) + (t2 > h3) + (t3 > h3); }

    ROT_ACC(QP_ROT1, 1)
    ROT_ACC(QP_XOR2, 2)
    ROT_ACC(QP_ROT3, 3)
#undef ROT_ACC

    // group max (== max of kept, since top-1 is kept)
    float m = fmaxf(fmaxf(s[0], s[1]), fmaxf(s[2], s[3]));
    m = fmaxf(m, dpp_f<QP_XOR1>(m));
    m = fmaxf(m, dpp_f<QP_XOR2>(m));

    const float e0 = (r[0] < TOPK) ? __expf(s[0] - m) : 0.f;
    const float e1 = (r[1] < TOPK) ? __expf(s[1] - m) : 0.f;
    const float e2 = (r[2] < TOPK) ? __expf(s[2] - m) : 0.f;
    const float e3 = (r[3] < TOPK) ? __expf(s[3] - m) : 0.f;

    const float den = qsum((e0 + e1) + (e2 + e3));      // in [1,4]
    const float rd = __builtin_amdgcn_rcpf(den);

    X  = qsum(fmaf(e3, xv[3], fmaf(e2, xv[2], fmaf(e1, xv[1], e0 * xv[0])))) * rd;
    Lo = qsum(fmaf(e3, lx[3], fmaf(e2, lx[2], fmaf(e1, lx[1], e0 * lx[0])))) * rd;
    A  = qsum(fmaf(e3, ce[3], fmaf(e2, ce[2], fmaf(e1, ce[1], e0 * ce[0])))) * rd;
}

// ---------------- fused kernel: per-block weight contraction + float4 main ----------------
__global__ __launch_bounds__(256) void UltraSparseGNN_fused(
    const float* __restrict__ x,
    const float* __restrict__ w_in,
    const float* __restrict__ emb,
    const float* __restrict__ w0,
    const float* __restrict__ a0,
    const float* __restrict__ w1,
    const float* __restrict__ a1,
    const float* __restrict__ w_out,
    const float* __restrict__ b_out,
    const float* __restrict__ r_int,
    float* __restrict__ out,
    int total4)
{
    __shared__ float g0[32], g1[32], c0[32], c1[32], gs[32];
    __shared__ float sc[10];
    __shared__ float tg0[16], tg1[16], tce0[16], tce1[16], tke[16];

    const int tid = threadIdx.x;

    // ---- per-block setup (~5 small matvecs; weights are tiny and L2-resident) ----
    {
        const int kk = tid & 31, grp = tid >> 5;
        if (grp == 0) { float a = 0; for (int j = 0; j < 32; ++j) a = fmaf(w_out[j],  w0[j*32+kk], a); g0[kk] = a; }
        if (grp == 1) { float a = 0; for (int j = 0; j < 32; ++j) a = fmaf(w_out[j],  w1[j*32+kk], a); g1[kk] = a; }
        if (grp == 2) { float a = 0; for (int j = 0; j < 32; ++j) a = fmaf(a0[32+j],  w0[j*32+kk], a); c0[kk] = a; }
        if (grp == 3) { float a = 0; for (int j = 0; j < 32; ++j) a = fmaf(a1[32+j],  w1[j*32+kk], a); c1[kk] = a; }
        __syncthreads();
        if (grp == 0) { float a = g0[kk]; for (int j = 0; j < 32; ++j) a = fmaf(g1[j], w0[j*32+kk], a); gs[kk] = a; }
        __syncthreads();
        if (tid < 10) {
            float acc = 0;
            switch (tid) {
                case 0: for (int j=0;j<32;++j) acc = fmaf(w_in[2*j],   c0[j],    acc); break; // alpha0
                case 1: for (int j=0;j<32;++j) acc = fmaf(w_in[2*j+1], c0[j],    acc); break; // beta0
                case 2: for (int j=0;j<32;++j) acc = fmaf(w_in[2*j],   c1[j],    acc); break; // alpha1
                case 3: for (int j=0;j<32;++j) acc = fmaf(w_in[2*j+1], c1[j],    acc); break; // beta1
                case 4: for (int j=0;j<32;++j) acc = fmaf(w_in[2*j],   w_out[j], acc); break; // kx
                case 5: for (int j=0;j<32;++j) acc = fmaf(w_in[2*j+1], w_out[j], acc); break; // kl
                case 6: for (int j=0;j<32;++j) acc = fmaf(w_in[2*j],   gs[j],    acc); break; // C0X
                case 7: for (int j=0;j<32;++j) acc = fmaf(w_in[2*j+1], gs[j],    acc); break; // C0L
                case 8: for (int j=0;j<32;++j) acc = fmaf(w_in[2*j],   g1[j],    acc); break; // C1X
                case 9: for (int j=0;j<32;++j) acc = fmaf(w_in[2*j+1], g1[j],    acc); break; // C1L
            }
            sc[tid] = acc;
        }
        if (tid >= 16 && tid < 32) { int n=tid-16; float a=0; for (int j=0;j<32;++j) a=fmaf(emb[n*32+j], c0[j], a); tg0[n]=a; }
        if (tid >= 32 && tid < 48) { int n=tid-32; float a=0; for (int j=0;j<32;++j) a=fmaf(emb[n*32+j], c1[j], a); tg1[n]=a; }
        if (tid >= 48 && tid < 64) { int n=tid-48; float a=0; for (int j=0;j<32;++j) a=fmaf(emb[n*32+j], gs[j], a); tce0[n]=a; }
        if (tid >= 64 && tid < 80) { int n=tid-64; float a=0; for (int j=0;j<32;++j) a=fmaf(emb[n*32+j], g1[j], a); tce1[n]=a; }
        if (tid >= 80 && tid < 96) { int n=tid-80; float a=0; for (int j=0;j<32;++j) a=fmaf(emb[n*32+j], w_out[j], a); tke[n]=a + b_out[0] + r_int[n]; }
        __syncthreads();
    }

    const int idx4 = blockIdx.x * 256 + tid;  // float4 index; 4 consecutive nodes of one graph
    if (idx4 >= total4) return;
    const int q = tid & 3;                    // quad position: nodes q*4 .. q*4+3

    const float4 xv4 = reinterpret_cast<const float4*>(x)[idx4];
    float xv[4] = {xv4.x, xv4.y, xv4.z, xv4.w};
    float lx[4];
    #pragma unroll
    for (int i = 0; i < 4; ++i) lx[i] = __logf(fmaxf(xv[i], 1e-6f));

    const float A0c = sc[0], B0c = sc[1], A1c = sc[2], B1c = sc[3];
    const float KX = sc[4], KL = sc[5], C0X = sc[6], C0L = sc[7], C1X = sc[8], C1L = sc[9];

    float gq0[4], gq1[4], ce0v[4], ce1v[4], kev[4];
    #pragma unroll
    for (int i = 0; i < 4; ++i) {
        gq0[i] = tg0[q*4+i];  gq1[i] = tg1[q*4+i];
        ce0v[i] = tce0[q*4+i]; ce1v[i] = tce1[q*4+i]; kev[i] = tke[q*4+i];
    }

    float s0[4], s1[4];
    #pragma unroll
    for (int i = 0; i < 4; ++i) {
        s0[i] = fmaf(A0c, xv[i], fmaf(B0c, lx[i], gq0[i]));
        s1[i] = fmaf(A1c, xv[i], fmaf(B1c, lx[i], gq1[i]));
    }

    float X0, L0, A0v, X1, L1, A1v;
    gat4(s0, xv, lx, ce0v, q, X0, L0, A0v);
    gat4(s1, xv, lx, ce1v, q, X1, L1, A1v);

    const float base = fmaf(X0, C0X, fmaf(L0, C0L, A0v)) + fmaf(X1, C1X, fmaf(L1, C1L, A1v));
    float4 o;
    o.x = fmaf(KX, xv[0], fmaf(KL, lx[0], kev[0] + base));
    o.y = fmaf(KX, xv[1], fmaf(KL, lx[1], kev[1] + base));
    o.z = fmaf(KX, xv[2], fmaf(KL, lx[2], kev[2] + base));
    o.w = fmaf(KX, xv[3], fmaf(KL, lx[3], kev[3] + base));
    reinterpret_cast<float4*>(out)[idx4] = o;
}

extern "C" void kernel_launch(void* const* d_in, const int* in_sizes, int n_in,
                              void* d_out, int out_size, void* d_ws, size_t ws_size,
                              hipStream_t stream) {
    const float* x     = (const float*)d_in[0];
    const float* w_in  = (const float*)d_in[1];
    const float* emb   = (const float*)d_in[2];
    const float* w0    = (const float*)d_in[3];
    const float* a0    = (const float*)d_in[4];
    const float* w1    = (const float*)d_in[5];
    const float* a1    = (const float*)d_in[6];
    const float* w_out = (const float*)d_in[7];
    const float* b_out = (const float*)d_in[8];
    const float* r_int = (const float*)d_in[9];

    const int total  = in_sizes[0];           // B*T*N = 1048576 (multiple of 16)
    const int total4 = total >> 2;
    const int blocks = (total4 + 255) / 256;  // 1024
    UltraSparseGNN_fused<<<blocks, 256, 0, stream>>>(
        x, w_in, emb, w0, a0, w1, a1, w_out, b_out, r_int,
        (float*)d_out, total4);
}

// Round 5
// 12.740 us; speedup vs baseline: 6.1990x; 1.2703x over previous
//
#include <hip/hip_runtime.h>

// ---------------- quad DPP helpers (4-lane groups = one 16-node graph) ----------------
#define QP_XOR1 0xB1   // [1,0,3,2]
#define QP_XOR2 0x4E   // [2,3,0,1]

template<int CTRL>
__device__ __forceinline__ float dpp_f(float v) {
    return __builtin_bit_cast(float,
        __builtin_amdgcn_update_dpp(0, __builtin_bit_cast(int, v), CTRL, 0xF, 0xF, true));
}
__device__ __forceinline__ float qsum(float v) {    // sum over quad, result in all 4 lanes
    v += dpp_f<QP_XOR1>(v);
    v += dpp_f<QP_XOR2>(v);
    return v;
}

// partial bitonic merge: this lane's sorted-desc 4 list with DPP partner's -> top-4 of union
template<int CTRL>
__device__ __forceinline__ void merge4(float& t0, float& t1, float& t2, float& t3) {
    const float p0 = dpp_f<CTRL>(t0), p1 = dpp_f<CTRL>(t1), p2 = dpp_f<CTRL>(t2), p3 = dpp_f<CTRL>(t3);
    const float c0 = fmaxf(t0, p3), c1 = fmaxf(t1, p2), c2 = fmaxf(t2, p1), c3 = fmaxf(t3, p0);
    const float d0 = fmaxf(c0, c2), d2 = fminf(c0, c2);   // bitonic clean
    const float d1 = fmaxf(c1, c3), d3 = fminf(c1, c3);
    t0 = fmaxf(d0, d1); t1 = fminf(d0, d1);
    t2 = fmaxf(d2, d3); t3 = fminf(d2, d3);
}

// collapsed GAT layer: s[4] = this lane's node scores; returns attn-weighted sums
// X = sum attn*x, Lo = sum attn*lnx, A = sum attn*ce  (quad-uniform).
// top-4 selection via threshold tau = 4th largest of 16 (exact ties measure-zero here).
__device__ __forceinline__ void gat4(const float s[4], const float xv[4], const float lx[4],
                                     const float4 ce, float& X, float& Lo, float& A) {
    // sort own 4 descending (5-comparator network)
    const float a0 = fmaxf(s[0], s[1]), a1 = fminf(s[0], s[1]);
    const float a2 = fmaxf(s[2], s[3]), a3 = fminf(s[2], s[3]);
    const float b0 = fmaxf(a0, a2), b2 = fminf(a0, a2);
    const float b1 = fmaxf(a1, a3), b3 = fminf(a1, a3);
    float t0 = b0, t1 = fmaxf(b1, b2), t2 = fminf(b1, b2), t3 = b3;
    merge4<QP_XOR1>(t0, t1, t2, t3);   // top-4 of 8
    merge4<QP_XOR2>(t0, t1, t2, t3);   // top-4 of 16 (all lanes agree)
    const float m = t0, tau = t3;
    const float e0 = (s[0] >= tau) ? __expf(s[0] - m) : 0.f;
    const float e1 = (s[1] >= tau) ? __expf(s[1] - m) : 0.f;
    const float e2 = (s[2] >= tau) ? __expf(s[2] - m) : 0.f;
    const float e3 = (s[3] >= tau) ? __expf(s[3] - m) : 0.f;
    const float rd = __builtin_amdgcn_rcpf(qsum((e0 + e1) + (e2 + e3)));  // den in [1,4]
    X  = qsum(fmaf(e3, xv[3], fmaf(e2, xv[2], fmaf(e1, xv[1], e0 * xv[0])))) * rd;
    Lo = qsum(fmaf(e3, lx[3], fmaf(e2, lx[2], fmaf(e1, lx[1], e0 * lx[0])))) * rd;
    A  = qsum(fmaf(e3, ce.w,  fmaf(e2, ce.z,  fmaf(e1, ce.y,  e0 * ce.x)))) * rd;
}

// ---------------- LDS layout (floats) ----------------
#define U_WOUT 0
#define U_A0H  32
#define U_A1H  64
#define U_G0   96
#define U_G1   128
#define U_C0   160
#define U_C1   192
#define U_GS   224
#define LBR    256   // 16: b_out + r_int[n]
#define LZERO  272
#define LDUMP  288   // 256 scratch slots for idle lanes
#define LCST   544   // [0..9] scalars; +16 tg0; +32 tg1; +48 tce0; +64 tce1; +80 tke
#define LDS_FLOATS 704

// unified setup dot: L[dst] = sum_j L[uoff+j] * vb[j*vstr]  + L[eoff]
__device__ __forceinline__ void job32(float* L, int uoff, const float* __restrict__ vb,
                                      int vstr, int dst, int eoff) {
    float acc = 0.f;
    #pragma unroll
    for (int j = 0; j < 32; ++j) acc = fmaf(L[uoff + j], vb[j * vstr], acc);
    L[dst] = acc + L[eoff];
}

__device__ __forceinline__ void eval_graph(
    const float4 xv4, const float4 g0q, const float4 g1q,
    const float4 ce0q, const float4 ce1q, const float4 keq,
    float A0c, float B0c, float A1c, float B1c,
    float KX, float KL, float C0X, float C0L, float C1X, float C1L,
    float4& o)
{
    float xv[4] = {xv4.x, xv4.y, xv4.z, xv4.w};
    float lx[4], s0[4], s1[4];
    const float g0a[4] = {g0q.x, g0q.y, g0q.z, g0q.w};
    const float g1a[4] = {g1q.x, g1q.y, g1q.z, g1q.w};
    #pragma unroll
    for (int i = 0; i < 4; ++i) {
        lx[i] = __logf(fmaxf(xv[i], 1e-6f));
        s0[i] = fmaf(A0c, xv[i], fmaf(B0c, lx[i], g0a[i]));
        s1[i] = fmaf(A1c, xv[i], fmaf(B1c, lx[i], g1a[i]));
    }
    float X0, L0, A0v, X1, L1, A1v;
    gat4(s0, xv, lx, ce0q, X0, L0, A0v);
    gat4(s1, xv, lx, ce1q, X1, L1, A1v);
    const float base = fmaf(X0, C0X, fmaf(L0, C0L, A0v)) + fmaf(X1, C1X, fmaf(L1, C1L, A1v));
    o.x = fmaf(KX, xv[0], fmaf(KL, lx[0], keq.x + base));
    o.y = fmaf(KX, xv[1], fmaf(KL, lx[1], keq.y + base));
    o.z = fmaf(KX, xv[2], fmaf(KL, lx[2], keq.z + base));
    o.w = fmaf(KX, xv[3], fmaf(KL, lx[3], keq.w + base));
}

__global__ __launch_bounds__(256) void UltraSparseGNN_fused(
    const float* __restrict__ x,
    const float* __restrict__ w_in,
    const float* __restrict__ emb,
    const float* __restrict__ w0,
    const float* __restrict__ a0,
    const float* __restrict__ w1,
    const float* __restrict__ a1,
    const float* __restrict__ w_out,
    const float* __restrict__ b_out,
    const float* __restrict__ r_int,
    float* __restrict__ out,
    int total4, int half)
{
    __shared__ __align__(16) float L[LDS_FLOATS];
    const int tid = threadIdx.x;

    // ---- stage small u-vectors (parallel, one masked set) ----
    if (tid < 32)        L[U_WOUT + tid]      = w_out[tid];
    else if (tid < 64)   L[U_A0H + tid - 32]  = a0[32 + tid - 32];
    else if (tid < 96)   L[U_A1H + tid - 64]  = a1[32 + tid - 64];
    else if (tid < 112)  L[LBR + tid - 96]    = r_int[tid - 96] + b_out[0];
    else if (tid == 112) L[LZERO]             = 0.f;
    __syncthreads();

    // ---- phase B1: g0, g1, c0, c1, tke, kx, kl (all concurrent, one uniform loop) ----
    {
        int uoff = U_WOUT, vstr = 0, dst = LDUMP + tid, eoff = LZERO;
        const float* vb = w0;
        if (tid < 32)        { vb = w0 + tid;              vstr = 32; dst = U_G0 + tid; }
        else if (tid < 64)   { vb = w1 + (tid - 32);       vstr = 32; dst = U_G1 + (tid - 32); }
        else if (tid < 96)   { uoff = U_A0H; vb = w0 + (tid - 64); vstr = 32; dst = U_C0 + (tid - 64); }
        else if (tid < 128)  { uoff = U_A1H; vb = w1 + (tid - 96); vstr = 32; dst = U_C1 + (tid - 96); }
        else if (tid < 144)  { vb = emb + (tid - 128) * 32; vstr = 1; dst = LCST + 80 + (tid - 128); eoff = LBR + (tid - 128); }
        else if (tid == 144) { vb = w_in;     vstr = 2; dst = LCST + 4; }   // kx
        else if (tid == 145) { vb = w_in + 1; vstr = 2; dst = LCST + 5; }   // kl
        job32(L, uoff, vb, vstr, dst, eoff);
    }
    __syncthreads();

    // ---- phase B2: gs, tg0, tg1, tce1, scalars 0-3,8,9 ----
    {
        int uoff = U_G1, vstr = 0, dst = LDUMP + tid, eoff = LZERO;
        const float* vb = w0;
        if (tid < 32)        { vb = w0 + tid; vstr = 32; dst = U_GS + tid; eoff = U_G0 + tid; }
        else if (tid < 48)   { uoff = U_C0; vb = emb + (tid - 32) * 32; vstr = 1; dst = LCST + 16 + (tid - 32); }
        else if (tid < 64)   { uoff = U_C1; vb = emb + (tid - 48) * 32; vstr = 1; dst = LCST + 32 + (tid - 48); }
        else if (tid < 80)   { vb = emb + (tid - 64) * 32; vstr = 1; dst = LCST + 64 + (tid - 64); }
        else if (tid == 80)  { uoff = U_C0; vb = w_in;     vstr = 2; dst = LCST + 0; }
        else if (tid == 81)  { uoff = U_C0; vb = w_in + 1; vstr = 2; dst = LCST + 1; }
        else if (tid == 82)  { uoff = U_C1; vb = w_in;     vstr = 2; dst = LCST + 2; }
        else if (tid == 83)  { uoff = U_C1; vb = w_in + 1; vstr = 2; dst = LCST + 3; }
        else if (tid == 84)  { vb = w_in;     vstr = 2; dst = LCST + 8; }
        else if (tid == 85)  { vb = w_in + 1; vstr = 2; dst = LCST + 9; }
        job32(L, uoff, vb, vstr, dst, eoff);
    }
    __syncthreads();

    // ---- phase B3: tce0, C0X, C0L (need gs) ----
    {
        int vstr = 0, dst = LDUMP + tid;
        const float* vb = w0;
        if (tid < 16)        { vb = emb + tid * 32; vstr = 1; dst = LCST + 48 + tid; }
        else if (tid == 16)  { vb = w_in;     vstr = 2; dst = LCST + 6; }
        else if (tid == 17)  { vb = w_in + 1; vstr = 2; dst = LCST + 7; }
        job32(L, U_GS, vb, vstr, dst, LZERO);
    }
    __syncthreads();

    // ---- main: 2 graphs per thread, same quad position q (tables shared) ----
    const int tA = blockIdx.x * 256 + tid;
    if (tA >= total4) return;
    const int q = tid & 3;

    const float4 scA = *reinterpret_cast<const float4*>(&L[LCST + 0]); // A0c,B0c,A1c,B1c
    const float4 scB = *reinterpret_cast<const float4*>(&L[LCST + 4]); // KX,KL,C0X,C0L
    const float C1X = L[LCST + 8], C1L = L[LCST + 9];
    const float4 g0q  = *reinterpret_cast<const float4*>(&L[LCST + 16 + q * 4]);
    const float4 g1q  = *reinterpret_cast<const float4*>(&L[LCST + 32 + q * 4]);
    const float4 ce0q = *reinterpret_cast<const float4*>(&L[LCST + 48 + q * 4]);
    const float4 ce1q = *reinterpret_cast<const float4*>(&L[LCST + 64 + q * 4]);
    const float4 keq  = *reinterpret_cast<const float4*>(&L[LCST + 80 + q * 4]);

    const float4 xvA = reinterpret_cast<const float4*>(x)[tA];
    const int tB = tA + half;
    const bool doB = (tB < total4);
    float4 xvB = xvA;
    if (doB) xvB = reinterpret_cast<const float4*>(x)[tB];

    float4 oA, oB;
    eval_graph(xvA, g0q, g1q, ce0q, ce1q, keq,
               scA.x, scA.y, scA.z, scA.w, scB.x, scB.y, scB.z, scB.w, C1X, C1L, oA);
    eval_graph(xvB, g0q, g1q, ce0q, ce1q, keq,
               scA.x, scA.y, scA.z, scA.w, scB.x, scB.y, scB.z, scB.w, C1X, C1L, oB);

    reinterpret_cast<float4*>(out)[tA] = oA;
    if (doB) reinterpret_cast<float4*>(out)[tB] = oB;
}

extern "C" void kernel_launch(void* const* d_in, const int* in_sizes, int n_in,
                              void* d_out, int out_size, void* d_ws, size_t ws_size,
                              hipStream_t stream) {
    const float* x     = (const float*)d_in[0];
    const float* w_in  = (const float*)d_in[1];
    const float* emb   = (const float*)d_in[2];
    const float* w0    = (const float*)d_in[3];
    const float* a0    = (const float*)d_in[4];
    const float* w1    = (const float*)d_in[5];
    const float* a1    = (const float*)d_in[6];
    const float* w_out = (const float*)d_in[7];
    const float* b_out = (const float*)d_in[8];
    const float* r_int = (const float*)d_in[9];

    const int total  = in_sizes[0];                 // B*T*N = 1048576 (mult of 16)
    const int total4 = total >> 2;                  // float4 count (mult of 4)
    const int half   = (((total4 + 1) >> 1) + 3) & ~3;  // mult of 4 so quad pos matches
    const int blocks = (half + 255) / 256;          // 512 for the bench shape
    UltraSparseGNN_fused<<<blocks, 256, 0, stream>>>(
        x, w_in, emb, w0, a0, w1, a1, w_out, b_out, r_int,
        (float*)d_out, total4, half);
}